// Round 1
// baseline (10.616 us; speedup 1.0000x reference)
//
#include <hip/hip_runtime.h>

#define IN_F   512
#define OUT_F  1024
#define NR     16      // distinct weight rows used (ROW_IDX[j] = j % 16)
#define NG     32      // elements per residue class (512 / 16)
#define DELTA  0.1f

// One block per batch row b (128 blocks, 1024 threads).
// Phase 1: threads 0..511 reduce x[b,:] into per-residue stats:
//   sx[r]  = sum_g |x[b, g*16+r]|
//   sxm[r] = sum_g x*(x>=-1)
//   mx[r]  = max_g |x[b, g*16+r]|
// Phase 2: thread o computes out[b,o] from 16 weight rows:
//   out = sum_r w[r,o]*sxm[r] + DELTA*( max_r |w[r,o]|*mx[r] - sum_r |w[r,o]|*sx[r] )
__global__ __launch_bounds__(1024)
void conj_kernel(const float* __restrict__ x,
                 const float* __restrict__ w,
                 float* __restrict__ out) {
    __shared__ float s_sx[NR];
    __shared__ float s_sxm[NR];
    __shared__ float s_mx[NR];

    const int b = blockIdx.x;
    const int t = threadIdx.x;

    if (t < IN_F) {
        const int r = t >> 5;   // 0..15  (residue class)
        const int g = t & 31;   // 0..31  (group index)
        const float xv = x[b * IN_F + g * NR + r];
        const float ax = fabsf(xv);
        const float xm = (xv >= -1.0f) ? xv : 0.0f;

        float sx = ax, sm = xm, mx = ax;
        // 32-lane butterfly; xor masks <32 stay within each 32-lane half of the
        // 64-lane wave, and each residue team is a contiguous 32-lane span.
        #pragma unroll
        for (int m = 16; m >= 1; m >>= 1) {
            sx += __shfl_xor(sx, m);
            sm += __shfl_xor(sm, m);
            mx = fmaxf(mx, __shfl_xor(mx, m));
        }
        if (g == 0) {
            s_sx[r]  = sx;
            s_sxm[r] = sm;
            s_mx[r]  = mx;
        }
    }
    __syncthreads();

    const int o = t;            // 0..1023, one output column per thread
    float acc = 0.0f;           // masked matmul term
    float sab = 0.0f;           // sum of |W*x|
    float mxv = 0.0f;           // max of |W*x| (all products >= 0)
    #pragma unroll
    for (int r = 0; r < NR; ++r) {
        const float wv = w[r * OUT_F + o];   // coalesced across threads
        const float aw = fabsf(wv);
        acc += wv * s_sxm[r];
        sab += aw * s_sx[r];
        mxv = fmaxf(mxv, aw * s_mx[r]);
    }
    out[b * OUT_F + o] = acc + DELTA * (mxv - sab);
}

extern "C" void kernel_launch(void* const* d_in, const int* in_sizes, int n_in,
                              void* d_out, int out_size, void* d_ws, size_t ws_size,
                              hipStream_t stream) {
    const float* x = (const float*)d_in[0];   // (128, 512)  f32
    const float* w = (const float*)d_in[1];   // (32, 1024)  f32
    float* out = (float*)d_out;               // (128, 1024) f32
    conj_kernel<<<128, 1024, 0, stream>>>(x, w, out);
}

// Round 2
// 9.373 us; speedup vs baseline: 1.1327x; 1.1327x over previous
//
#include <hip/hip_runtime.h>

#define IN_F   512
#define OUT_F  1024
#define NR     16      // distinct weight rows used (ROW_IDX[j] = j % 16)
#define DELTA  0.1f

// 2048 blocks x 64 threads: block = (batch row b, 64-wide output chunk).
// Lane l loads x[b, l + 64k] (k=0..7, fully coalesced); all 8 elements have
// residue l%16, so per-residue stats finalize with shfl_xor(16),(32) —
// no LDS, no barriers. Phase 2 broadcasts via __shfl(v, const r) = readlane.
__global__ __launch_bounds__(64)
void conj_kernel(const float* __restrict__ x,
                 const float* __restrict__ w,
                 float* __restrict__ out) {
    const int bid   = blockIdx.x;
    const int b     = bid >> 4;        // 0..127
    const int chunk = bid & 15;        // 0..15  (64 outputs each)
    const int l     = threadIdx.x;     // 0..63
    const int o     = chunk * 64 + l;  // output column

    // Issue weight loads first — independent of x, latency overlaps the
    // x-load + reduce chain. Rows 0..15 only (ROW_IDX[j] = j % 16).
    float wv[NR];
    #pragma unroll
    for (int r = 0; r < NR; ++r)
        wv[r] = w[r * OUT_F + o];      // coalesced 256B per wave

    const float* xrow = x + b * IN_F;
    float sx = 0.0f;   // sum |x| for residue l%16
    float sm = 0.0f;   // sum x*(x>=-1)
    float mx = 0.0f;   // max |x|
    #pragma unroll
    for (int k = 0; k < 8; ++k) {
        const float xv = xrow[l + 64 * k];   // coalesced
        const float ax = fabsf(xv);
        sx += ax;
        sm += (xv >= -1.0f) ? xv : 0.0f;
        mx = fmaxf(mx, ax);
    }
    // Combine lanes {r, r+16, r+32, r+48} -> every lane holds full stats
    // for residue l%16.
    sx += __shfl_xor(sx, 16);
    sm += __shfl_xor(sm, 16);
    mx = fmaxf(mx, __shfl_xor(mx, 16));
    sx += __shfl_xor(sx, 32);
    sm += __shfl_xor(sm, 32);
    mx = fmaxf(mx, __shfl_xor(mx, 32));

    float acc = 0.0f;   // masked matmul
    float sab = 0.0f;   // sum |W*x|
    float mxv = 0.0f;   // max |W*x|
    #pragma unroll
    for (int r = 0; r < NR; ++r) {
        const float sm_r = __shfl(sm, r);   // lane r holds residue r (r < 16)
        const float sx_r = __shfl(sx, r);
        const float mx_r = __shfl(mx, r);
        const float aw = fabsf(wv[r]);
        acc += wv[r] * sm_r;
        sab += aw * sx_r;
        mxv = fmaxf(mxv, aw * mx_r);
    }
    out[b * OUT_F + o] = acc + DELTA * (mxv - sab);
}

extern "C" void kernel_launch(void* const* d_in, const int* in_sizes, int n_in,
                              void* d_out, int out_size, void* d_ws, size_t ws_size,
                              hipStream_t stream) {
    const float* x = (const float*)d_in[0];   // (128, 512)  f32
    const float* w = (const float*)d_in[1];   // (32, 1024)  f32
    float* out = (float*)d_out;               // (128, 1024) f32
    conj_kernel<<<2048, 64, 0, stream>>>(x, w, out);
}